// Round 5
// baseline (863.184 us; speedup 1.0000x reference)
//
#include <hip/hip_runtime.h>

#define B_TOT 8192
#define T_OBS 128
#define T_FUT 64
#define T_ALL 192
#define DIN 5
#define HD 128
#define BT 32          // batch rows per block (two 16-row tiles)
#define LDSTR 136      // LDS row stride in shorts (272 B, 16B-aligned rows)
#define NTHR 1024      // 16 waves: 4 waves/SIMD co-resident by construction

#define LOG2E 1.44269504088896340736f

typedef __attribute__((ext_vector_type(8))) short short8;
typedef __attribute__((ext_vector_type(4))) float f32x4;
typedef __attribute__((ext_vector_type(2))) unsigned int u32x2;
typedef __attribute__((ext_vector_type(4))) unsigned int u32x4;

__device__ inline short f2bf(float f) {
    unsigned u = __float_as_uint(f);
    u += 0x7FFFu + ((u >> 16) & 1u);   // round-to-nearest-even
    return (short)(u >> 16);
}

// packed f32->bf16 (RNE), lo <- s0, hi <- s1
__device__ inline unsigned cvtpk(float lo, float hi) {
    unsigned r;
    asm volatile("v_cvt_pk_bf16_f32 %0, %1, %2" : "=v"(r) : "v"(lo), "v"(hi));
    return r;
}

__device__ inline f32x4 MFMA(short8 a, short8 b, f32x4 c) {
    return __builtin_amdgcn_mfma_f32_16x16x32_bf16(a, b, c, 0, 0, 0);
}

__device__ inline short8 load_w8s(const float* p, float s) {
    float4 a = *reinterpret_cast<const float4*>(p);
    float4 b = *reinterpret_cast<const float4*>(p + 4);
    short8 r;
    r[0] = f2bf(a.x * s); r[1] = f2bf(a.y * s); r[2] = f2bf(a.z * s); r[3] = f2bf(a.w * s);
    r[4] = f2bf(b.x * s); r[5] = f2bf(b.y * s); r[6] = f2bf(b.z * s); r[7] = f2bf(b.w * s);
    return r;
}
__device__ inline short8 load_w5s(const float* p, float s) {
    short8 r = (short8)0;
    r[0] = f2bf(p[0] * s); r[1] = f2bf(p[1] * s); r[2] = f2bf(p[2] * s);
    r[3] = f2bf(p[3] * s); r[4] = f2bf(p[4] * s);
    return r;
}

// 1024 threads = 16 waves, 256 blocks = 1 block/CU = 4 waves/SIMD.
// R3 (8 waves, 2/SIMD) measured 3750 cyc/step vs a ~1300-cyc cross-pipe
// throughput floor -> latency/serialization bound. This version keeps R3's
// per-wave register budget (15 short8 weights = 60 VGPR; R4's 30-frag
// version spilled catastrophically) but doubles resident waves/SIMD:
// wave w owns batch half a = w>>3 and gate-cols 16*(w&7)..+16 of r/z/n.
// Per-wave step work halves (15 MFMA, 4 elems, 4 KB LDS read); 4-way wave
// interleave hides the per-wave read->MFMA->trans serial chain.
// Register relief: biases live in per-wave LDS slots (4 broadcast b128
// reads/step, -16 VGPR, f32 precision kept); head weights live in LDS
// (written once, read by the rotating firing wave, -20 VGPR).
// Elementwise: combined denominator (validated R4): 3 exp2 + 2 rcp/elem.
__global__ __launch_bounds__(NTHR, 1)
void gru_tracemodel_kernel(const float* __restrict__ obs, const float* __restrict__ target,
                           const float* __restrict__ eWih, const float* __restrict__ eWhh,
                           const float* __restrict__ ebih, const float* __restrict__ ebhh,
                           const float* __restrict__ cWih, const float* __restrict__ cWhh,
                           const float* __restrict__ cbih, const float* __restrict__ cbhh,
                           const float* __restrict__ headW, const float* __restrict__ headb,
                           float* __restrict__ out)
{
    __shared__ __attribute__((aligned(16))) short Abuf[2][BT][LDSTR];
    __shared__ __attribute__((aligned(16))) short Hw[DIN][LDSTR];     // head W, bf16
    __shared__ __attribute__((aligned(16))) float BiasLds[16][4][4][4]; // [wave][g][q][r]
    __shared__ float HbLds[8];

    const int tid   = threadIdx.x;
    const int wave  = tid >> 6;    // 0..15
    const int lane  = tid & 63;
    const int q     = lane >> 4;   // k-group of A/B frags; row-group of C/D
    const int c     = lane & 15;   // non-K index of A/B frags; col of C/D
    const int b0    = blockIdx.x * BT;
    const int a     = wave >> 3;   // batch half-tile (0 or 1)
    const int w8    = wave & 7;    // gate-col slice
    const int wbase = w8 * 16;

    // h0 = 0
    for (int i = tid; i < 2 * BT * LDSTR; i += NTHR) ((short*)Abuf)[i] = 0;

    // ---- weight fragments (A-operand: lane holds W'[n = wbase+c][k]) ----
    // kt 0..3: Whh K-tiles; kt 4: zero-padded Wih x-tile (only q==0 nonzero)
    short8 Wr[5], Wz[5], Wn[5];

    auto load_phase = [&](const float* Wih, const float* Whh,
                          const float* bih, const float* bhh) {
        const int nr = 0 * HD + wbase + c;
        const int nz = 1 * HD + wbase + c;
        const int nn = 2 * HD + wbase + c;
        #pragma unroll
        for (int kt = 0; kt < 4; ++kt) {
            Wr[kt] = load_w8s(Whh + nr * HD + kt * 32 + q * 8, LOG2E);
            Wz[kt] = load_w8s(Whh + nz * HD + kt * 32 + q * 8, LOG2E);
            Wn[kt] = load_w8s(Whh + nn * HD + kt * 32 + q * 8, 2.f * LOG2E);
        }
        Wr[4] = (q == 0) ? load_w5s(Wih + nr * DIN, LOG2E) : (short8)0;
        Wz[4] = (q == 0) ? load_w5s(Wih + nz * DIN, LOG2E) : (short8)0;
        Wn[4] = (q == 0) ? load_w5s(Wih + nn * DIN, 2.f * LOG2E) : (short8)0;
        // biases -> this wave's LDS slot (f32, exact); lane c==0 of each q
        if (c == 0) {
            const int n0 = wbase + q * 4;
            f32x4 v0, v1, v2, v3;
            #pragma unroll
            for (int r = 0; r < 4; ++r) {
                v0[r] = (bih[0 * HD + n0 + r] + bhh[0 * HD + n0 + r]) * LOG2E;
                v1[r] = (bih[1 * HD + n0 + r] + bhh[1 * HD + n0 + r]) * LOG2E;
                v2[r] = bih[2 * HD + n0 + r] * (2.f * LOG2E);
                v3[r] = bhh[2 * HD + n0 + r] * (2.f * LOG2E);
            }
            *reinterpret_cast<f32x4*>(&BiasLds[wave][0][q][0]) = v0;
            *reinterpret_cast<f32x4*>(&BiasLds[wave][1][q][0]) = v1;
            *reinterpret_cast<f32x4*>(&BiasLds[wave][2][q][0]) = v2;
            *reinterpret_cast<f32x4*>(&BiasLds[wave][3][q][0]) = v3;
        }
    };
    load_phase(eWih, eWhh, ebih, ebhh);

    // head weights -> LDS once (wave 0); covered by first loop barrier
    if (wave == 0 && c < DIN) {
        #pragma unroll
        for (int kt = 0; kt < 4; ++kt) {
            short8 w = load_w8s(headW + c * HD + kt * 32 + q * 8, 1.f);
            *reinterpret_cast<short8*>(&Hw[c][kt * 32 + q * 8]) = w;
        }
    }
    if (tid < 8) HbLds[tid] = (tid < DIN) ? headb[tid] : 0.f;

    // fp32 carried h: hreg[r] = h[batch a*16+c][dim wbase+q*4+r]
    float hreg[4] = {0.f, 0.f, 0.f, 0.f};

    const float* obsr = obs    + (size_t)(b0 + a * 16 + c) * (T_OBS * DIN);
    const float* tgtr = target + (size_t)(b0 + a * 16 + c) * (T_FUT * DIN);
    float x5[5] = {0, 0, 0, 0, 0};
    if (q == 0) {
        #pragma unroll
        for (int j = 0; j < DIN; ++j) x5[j] = obsr[j];   // x_0
    }

    for (int t = 0; t <= T_ALL; ++t) {
        __syncthreads();
        const int p = t & 1;

        // h fragments (B-operand): lane holds h[batch a*16+c][k=kt*32+q*8..]
        short8 ah[4];
        const short* ap = &Abuf[p][a * 16 + c][0];
        #pragma unroll
        for (int kt = 0; kt < 4; ++kt)
            ah[kt] = *reinterpret_cast<const short8*>(ap + kt * 32 + q * 8);

        // fused head on previous step's h; firing wave rotates over the 8
        // gate-col slices; both batch halves fire (one wave each)
        if (t >= T_OBS + 1 && w8 == ((t - T_OBS - 1) & 7)) {
            const int s = t - (T_OBS + 1);
            const short* hwp = &Hw[(c < DIN) ? c : 0][0];
            f32x4 acc = {0.f, 0.f, 0.f, 0.f};
            #pragma unroll
            for (int kt = 0; kt < 4; ++kt) {
                short8 wh = *reinterpret_cast<const short8*>(hwp + kt * 32 + q * 8);
                acc = MFMA(wh, ah[kt], acc);
            }
            const int d0 = q * 4;
            if (d0 < DIN) {
                float* op = out + ((size_t)(b0 + a * 16 + c) * T_FUT + s) * DIN + d0;
                op[0] = acc[0] + HbLds[d0];
                if (q == 0) {
                    op[1] = acc[1] + HbLds[1];
                    op[2] = acc[2] + HbLds[2];
                    op[3] = acc[3] + HbLds[3];
                }
            }
        }
        if (t == T_ALL) break;

        if (t == T_OBS) load_phase(cWih, cWhh, cbih, cbhh);  // switch to cell

        // x fragment (5th K-tile, B-operand): q==0 lanes hold x[batch][0..4]
        short8 ax;
        {
            unsigned u0 = 0, u1 = 0, u2 = 0;
            if (q == 0) {
                u0 = cvtpk(x5[0], x5[1]);
                u1 = cvtpk(x5[2], x5[3]);
                u2 = cvtpk(x5[4], 0.f);
            }
            u32x4 va = {u0, u1, u2, 0u};
            ax = __builtin_bit_cast(short8, va);
            const int tn = t + 1;   // prefetch next step's x
            if (q == 0 && tn < T_ALL) {
                const float* px = (tn < T_OBS)  ? (obsr + tn * DIN)
                                : (tn == T_OBS) ? (obsr + (T_OBS - 1) * DIN)
                                                : (tgtr + (tn - T_OBS - 1) * DIN);
                #pragma unroll
                for (int j = 0; j < DIN; ++j) x5[j] = px[j];
            }
        }

        // bias C-init: per-wave LDS broadcast reads (same addr across c-lanes)
        const f32x4 bR  = *reinterpret_cast<const f32x4*>(&BiasLds[wave][0][q][0]);
        const f32x4 bZ  = *reinterpret_cast<const f32x4*>(&BiasLds[wave][1][q][0]);
        const f32x4 bNi = *reinterpret_cast<const f32x4*>(&BiasLds[wave][2][q][0]);
        const f32x4 bNh = *reinterpret_cast<const f32x4*>(&BiasLds[wave][3][q][0]);

        // gate MFMAs (A = weights, B = h): 15/wave/step
        f32x4 aR  = MFMA(Wr[0], ah[0], bR);
        f32x4 aZ  = MFMA(Wz[0], ah[0], bZ);
        f32x4 aNh = MFMA(Wn[0], ah[0], bNh);
        #pragma unroll
        for (int kt = 1; kt < 4; ++kt) {
            aR  = MFMA(Wr[kt], ah[kt], aR);
            aZ  = MFMA(Wz[kt], ah[kt], aZ);
            aNh = MFMA(Wn[kt], ah[kt], aNh);
        }
        aR  = MFMA(Wr[4], ax, aR);
        aZ  = MFMA(Wz[4], ax, aZ);
        f32x4 aNi = MFMA(Wn[4], ax, bNi);

        // elementwise: accumulators pre-scaled by log2e (2log2e for n).
        // rv = 1/(1+exp2(-aR)); y = aNi + rv*aNh; ey = exp2(y); ez = exp2(-aZ)
        // h' = (h*(1+ey) + ez*(ey-1)) / ((1+ez)*(1+ey))   [validated R4]
        float hn[4];
        #pragma unroll
        for (int r = 0; r < 4; ++r) {
            float er  = __builtin_amdgcn_exp2f(-aR[r]);
            float rv  = __builtin_amdgcn_rcpf(1.f + er);
            float yv  = fmaf(rv, aNh[r], aNi[r]);
            float ey  = __builtin_amdgcn_exp2f(yv);
            float ez  = __builtin_amdgcn_exp2f(-aZ[r]);
            float d2  = 1.f + ey;
            float d1  = 1.f + ez;
            float em1 = ey - 1.f;
            float num = fmaf(ez, em1, hreg[r] * d2);
            float h_  = num * __builtin_amdgcn_rcpf(d1 * d2);
            hreg[r] = h_;
            hn[r] = h_;
        }
        // writeback: 4 consecutive h-dims of one row -> one b64 store
        u32x2 wv = { cvtpk(hn[0], hn[1]), cvtpk(hn[2], hn[3]) };
        *reinterpret_cast<u32x2*>(&Abuf[1 - p][a * 16 + c][wbase + q * 4]) = wv;
    }
}

extern "C" void kernel_launch(void* const* d_in, const int* in_sizes, int n_in,
                              void* d_out, int out_size, void* d_ws, size_t ws_size,
                              hipStream_t stream)
{
    (void)in_sizes; (void)n_in; (void)d_ws; (void)ws_size; (void)out_size;
    gru_tracemodel_kernel<<<dim3(B_TOT / BT), dim3(NTHR), 0, stream>>>(
        (const float*)d_in[0],  (const float*)d_in[1],
        (const float*)d_in[2],  (const float*)d_in[3],
        (const float*)d_in[4],  (const float*)d_in[5],
        (const float*)d_in[6],  (const float*)d_in[7],
        (const float*)d_in[8],  (const float*)d_in[9],
        (const float*)d_in[10], (const float*)d_in[11],
        (float*)d_out);
}

// Round 6
// 854.941 us; speedup vs baseline: 1.0096x; 1.0096x over previous
//
#include <hip/hip_runtime.h>

#define B_TOT 8192
#define T_OBS 128
#define T_FUT 64
#define T_ALL 192
#define DIN 5
#define HD 128
#define BT 32          // batch rows per block (two 16-row tiles)
#define LDSTR 136      // LDS row stride in shorts (272 B, 16B-aligned rows)
#define NTHR 1024      // 16 waves: 4 waves/SIMD co-resident by construction

#define LOG2E 1.44269504088896340736f

typedef __attribute__((ext_vector_type(8))) short short8;
typedef __attribute__((ext_vector_type(4))) float f32x4;
typedef __attribute__((ext_vector_type(2))) unsigned int u32x2;
typedef __attribute__((ext_vector_type(4))) unsigned int u32x4;

__device__ inline short f2bf(float f) {
    unsigned u = __float_as_uint(f);
    u += 0x7FFFu + ((u >> 16) & 1u);   // round-to-nearest-even
    return (short)(u >> 16);
}

// packed f32->bf16 (RNE), lo <- s0, hi <- s1
__device__ inline unsigned cvtpk(float lo, float hi) {
    unsigned r;
    asm volatile("v_cvt_pk_bf16_f32 %0, %1, %2" : "=v"(r) : "v"(lo), "v"(hi));
    return r;
}

__device__ inline f32x4 MFMA(short8 a, short8 b, f32x4 c) {
    return __builtin_amdgcn_mfma_f32_16x16x32_bf16(a, b, c, 0, 0, 0);
}

__device__ inline short8 load_w8s(const float* p, float s) {
    float4 a = *reinterpret_cast<const float4*>(p);
    float4 b = *reinterpret_cast<const float4*>(p + 4);
    short8 r;
    r[0] = f2bf(a.x * s); r[1] = f2bf(a.y * s); r[2] = f2bf(a.z * s); r[3] = f2bf(a.w * s);
    r[4] = f2bf(b.x * s); r[5] = f2bf(b.y * s); r[6] = f2bf(b.z * s); r[7] = f2bf(b.w * s);
    return r;
}
__device__ inline short8 load_w5s(const float* p, float s) {
    short8 r = (short8)0;
    r[0] = f2bf(p[0] * s); r[1] = f2bf(p[1] * s); r[2] = f2bf(p[2] * s);
    r[3] = f2bf(p[3] * s); r[4] = f2bf(p[4] * s);
    return r;
}

// 1024 threads = 16 waves, 256 blocks = 1 block/CU = 4 waves/SIMD.
// Identical structure to R5 (which verified OccupancyPercent=45%), with
// ONE fix: amdgpu_waves_per_eu(4,4) pins the register allocator to the
// 4-waves/EU budget (512/4 = 128 VGPR). Without it the compiler targeted
// 8 waves/EU -> 64-reg cap -> 597 MB of scratch spill (R5 regression;
// same failure mode as R1). Per-wave live state ~120 regs: 15 short8
// weights (60) + ah (16) + gate accumulators (16) + hreg (4) + x5 (5) +
// addressing. Biases and head weights live in LDS to stay under 128.
// Wave w owns batch half a = w>>3, gate-cols 16*(w&7)..+16 of r/z/n:
// 15 MFMA + 4 elems/lane + 4 KB LDS read per wave per step; 4-way wave
// interleave per SIMD hides the serial read->MFMA->trans chain.
// Elementwise: combined denominator (validated R4): 3 exp2 + 2 rcp/elem.
__global__ __launch_bounds__(NTHR, 1)
__attribute__((amdgpu_waves_per_eu(4, 4)))
void gru_tracemodel_kernel(const float* __restrict__ obs, const float* __restrict__ target,
                           const float* __restrict__ eWih, const float* __restrict__ eWhh,
                           const float* __restrict__ ebih, const float* __restrict__ ebhh,
                           const float* __restrict__ cWih, const float* __restrict__ cWhh,
                           const float* __restrict__ cbih, const float* __restrict__ cbhh,
                           const float* __restrict__ headW, const float* __restrict__ headb,
                           float* __restrict__ out)
{
    __shared__ __attribute__((aligned(16))) short Abuf[2][BT][LDSTR];
    __shared__ __attribute__((aligned(16))) short Hw[DIN][LDSTR];     // head W, bf16
    __shared__ __attribute__((aligned(16))) float BiasLds[16][4][4][4]; // [wave][g][q][r]
    __shared__ float HbLds[8];

    const int tid   = threadIdx.x;
    const int wave  = tid >> 6;    // 0..15
    const int lane  = tid & 63;
    const int q     = lane >> 4;   // k-group of A/B frags; row-group of C/D
    const int c     = lane & 15;   // non-K index of A/B frags; col of C/D
    const int b0    = blockIdx.x * BT;
    const int a     = wave >> 3;   // batch half-tile (0 or 1)
    const int w8    = wave & 7;    // gate-col slice
    const int wbase = w8 * 16;

    // h0 = 0
    for (int i = tid; i < 2 * BT * LDSTR; i += NTHR) ((short*)Abuf)[i] = 0;

    // ---- weight fragments (A-operand: lane holds W'[n = wbase+c][k]) ----
    // kt 0..3: Whh K-tiles; kt 4: zero-padded Wih x-tile (only q==0 nonzero)
    short8 Wr[5], Wz[5], Wn[5];

    auto load_phase = [&](const float* Wih, const float* Whh,
                          const float* bih, const float* bhh) {
        const int nr = 0 * HD + wbase + c;
        const int nz = 1 * HD + wbase + c;
        const int nn = 2 * HD + wbase + c;
        #pragma unroll
        for (int kt = 0; kt < 4; ++kt) {
            Wr[kt] = load_w8s(Whh + nr * HD + kt * 32 + q * 8, LOG2E);
            Wz[kt] = load_w8s(Whh + nz * HD + kt * 32 + q * 8, LOG2E);
            Wn[kt] = load_w8s(Whh + nn * HD + kt * 32 + q * 8, 2.f * LOG2E);
        }
        Wr[4] = (q == 0) ? load_w5s(Wih + nr * DIN, LOG2E) : (short8)0;
        Wz[4] = (q == 0) ? load_w5s(Wih + nz * DIN, LOG2E) : (short8)0;
        Wn[4] = (q == 0) ? load_w5s(Wih + nn * DIN, 2.f * LOG2E) : (short8)0;
        // biases -> this wave's LDS slot (f32, exact); lane c==0 of each q
        if (c == 0) {
            const int n0 = wbase + q * 4;
            f32x4 v0, v1, v2, v3;
            #pragma unroll
            for (int r = 0; r < 4; ++r) {
                v0[r] = (bih[0 * HD + n0 + r] + bhh[0 * HD + n0 + r]) * LOG2E;
                v1[r] = (bih[1 * HD + n0 + r] + bhh[1 * HD + n0 + r]) * LOG2E;
                v2[r] = bih[2 * HD + n0 + r] * (2.f * LOG2E);
                v3[r] = bhh[2 * HD + n0 + r] * (2.f * LOG2E);
            }
            *reinterpret_cast<f32x4*>(&BiasLds[wave][0][q][0]) = v0;
            *reinterpret_cast<f32x4*>(&BiasLds[wave][1][q][0]) = v1;
            *reinterpret_cast<f32x4*>(&BiasLds[wave][2][q][0]) = v2;
            *reinterpret_cast<f32x4*>(&BiasLds[wave][3][q][0]) = v3;
        }
    };
    load_phase(eWih, eWhh, ebih, ebhh);

    // head weights -> LDS once (wave 0); covered by first loop barrier
    if (wave == 0 && c < DIN) {
        #pragma unroll
        for (int kt = 0; kt < 4; ++kt) {
            short8 w = load_w8s(headW + c * HD + kt * 32 + q * 8, 1.f);
            *reinterpret_cast<short8*>(&Hw[c][kt * 32 + q * 8]) = w;
        }
    }
    if (tid < 8) HbLds[tid] = (tid < DIN) ? headb[tid] : 0.f;

    // fp32 carried h: hreg[r] = h[batch a*16+c][dim wbase+q*4+r]
    float hreg[4] = {0.f, 0.f, 0.f, 0.f};

    const float* obsr = obs    + (size_t)(b0 + a * 16 + c) * (T_OBS * DIN);
    const float* tgtr = target + (size_t)(b0 + a * 16 + c) * (T_FUT * DIN);
    float x5[5] = {0, 0, 0, 0, 0};
    if (q == 0) {
        #pragma unroll
        for (int j = 0; j < DIN; ++j) x5[j] = obsr[j];   // x_0
    }

    for (int t = 0; t <= T_ALL; ++t) {
        __syncthreads();
        const int p = t & 1;

        // h fragments (B-operand): lane holds h[batch a*16+c][k=kt*32+q*8..]
        short8 ah[4];
        const short* ap = &Abuf[p][a * 16 + c][0];
        #pragma unroll
        for (int kt = 0; kt < 4; ++kt)
            ah[kt] = *reinterpret_cast<const short8*>(ap + kt * 32 + q * 8);

        // fused head on previous step's h; firing wave rotates over the 8
        // gate-col slices; both batch halves fire (one wave each)
        if (t >= T_OBS + 1 && w8 == ((t - T_OBS - 1) & 7)) {
            const int s = t - (T_OBS + 1);
            const short* hwp = &Hw[(c < DIN) ? c : 0][0];
            f32x4 acc = {0.f, 0.f, 0.f, 0.f};
            #pragma unroll
            for (int kt = 0; kt < 4; ++kt) {
                short8 wh = *reinterpret_cast<const short8*>(hwp + kt * 32 + q * 8);
                acc = MFMA(wh, ah[kt], acc);
            }
            const int d0 = q * 4;
            if (d0 < DIN) {
                float* op = out + ((size_t)(b0 + a * 16 + c) * T_FUT + s) * DIN + d0;
                op[0] = acc[0] + HbLds[d0];
                if (q == 0) {
                    op[1] = acc[1] + HbLds[1];
                    op[2] = acc[2] + HbLds[2];
                    op[3] = acc[3] + HbLds[3];
                }
            }
        }
        if (t == T_ALL) break;

        if (t == T_OBS) load_phase(cWih, cWhh, cbih, cbhh);  // switch to cell

        // x fragment (5th K-tile, B-operand): q==0 lanes hold x[batch][0..4]
        short8 ax;
        {
            unsigned u0 = 0, u1 = 0, u2 = 0;
            if (q == 0) {
                u0 = cvtpk(x5[0], x5[1]);
                u1 = cvtpk(x5[2], x5[3]);
                u2 = cvtpk(x5[4], 0.f);
            }
            u32x4 va = {u0, u1, u2, 0u};
            ax = __builtin_bit_cast(short8, va);
            const int tn = t + 1;   // prefetch next step's x
            if (q == 0 && tn < T_ALL) {
                const float* px = (tn < T_OBS)  ? (obsr + tn * DIN)
                                : (tn == T_OBS) ? (obsr + (T_OBS - 1) * DIN)
                                                : (tgtr + (tn - T_OBS - 1) * DIN);
                #pragma unroll
                for (int j = 0; j < DIN; ++j) x5[j] = px[j];
            }
        }

        // bias C-init: per-wave LDS broadcast reads (same addr across c-lanes)
        const f32x4 bR  = *reinterpret_cast<const f32x4*>(&BiasLds[wave][0][q][0]);
        const f32x4 bZ  = *reinterpret_cast<const f32x4*>(&BiasLds[wave][1][q][0]);
        const f32x4 bNi = *reinterpret_cast<const f32x4*>(&BiasLds[wave][2][q][0]);
        const f32x4 bNh = *reinterpret_cast<const f32x4*>(&BiasLds[wave][3][q][0]);

        // gate MFMAs (A = weights, B = h): 15/wave/step
        f32x4 aR  = MFMA(Wr[0], ah[0], bR);
        f32x4 aZ  = MFMA(Wz[0], ah[0], bZ);
        f32x4 aNh = MFMA(Wn[0], ah[0], bNh);
        #pragma unroll
        for (int kt = 1; kt < 4; ++kt) {
            aR  = MFMA(Wr[kt], ah[kt], aR);
            aZ  = MFMA(Wz[kt], ah[kt], aZ);
            aNh = MFMA(Wn[kt], ah[kt], aNh);
        }
        aR  = MFMA(Wr[4], ax, aR);
        aZ  = MFMA(Wz[4], ax, aZ);
        f32x4 aNi = MFMA(Wn[4], ax, bNi);

        // elementwise: accumulators pre-scaled by log2e (2log2e for n).
        // rv = 1/(1+exp2(-aR)); y = aNi + rv*aNh; ey = exp2(y); ez = exp2(-aZ)
        // h' = (h*(1+ey) + ez*(ey-1)) / ((1+ez)*(1+ey))   [validated R4]
        float hn[4];
        #pragma unroll
        for (int r = 0; r < 4; ++r) {
            float er  = __builtin_amdgcn_exp2f(-aR[r]);
            float rv  = __builtin_amdgcn_rcpf(1.f + er);
            float yv  = fmaf(rv, aNh[r], aNi[r]);
            float ey  = __builtin_amdgcn_exp2f(yv);
            float ez  = __builtin_amdgcn_exp2f(-aZ[r]);
            float d2  = 1.f + ey;
            float d1  = 1.f + ez;
            float em1 = ey - 1.f;
            float num = fmaf(ez, em1, hreg[r] * d2);
            float h_  = num * __builtin_amdgcn_rcpf(d1 * d2);
            hreg[r] = h_;
            hn[r] = h_;
        }
        // writeback: 4 consecutive h-dims of one row -> one b64 store
        u32x2 wv = { cvtpk(hn[0], hn[1]), cvtpk(hn[2], hn[3]) };
        *reinterpret_cast<u32x2*>(&Abuf[1 - p][a * 16 + c][wbase + q * 4]) = wv;
    }
}

extern "C" void kernel_launch(void* const* d_in, const int* in_sizes, int n_in,
                              void* d_out, int out_size, void* d_ws, size_t ws_size,
                              hipStream_t stream)
{
    (void)in_sizes; (void)n_in; (void)d_ws; (void)ws_size; (void)out_size;
    gru_tracemodel_kernel<<<dim3(B_TOT / BT), dim3(NTHR), 0, stream>>>(
        (const float*)d_in[0],  (const float*)d_in[1],
        (const float*)d_in[2],  (const float*)d_in[3],
        (const float*)d_in[4],  (const float*)d_in[5],
        (const float*)d_in[6],  (const float*)d_in[7],
        (const float*)d_in[8],  (const float*)d_in[9],
        (const float*)d_in[10], (const float*)d_in[11],
        (float*)d_out);
}

// Round 7
// 842.027 us; speedup vs baseline: 1.0251x; 1.0153x over previous
//
#include <hip/hip_runtime.h>

#define B_TOT 8192
#define T_OBS 128
#define T_FUT 64
#define T_ALL 192
#define DIN 5
#define HD 128
#define BT 32          // batch rows per block (two 16-row tiles)
#define LDSTR 136      // LDS row stride in shorts (272 B, 16B-aligned rows)
#define NTHR 1024      // 16 waves: 4 waves/SIMD co-resident by construction

#define LOG2E 1.44269504088896340736f

typedef __attribute__((ext_vector_type(8))) short short8;
typedef __attribute__((ext_vector_type(4))) float f32x4;
typedef __attribute__((ext_vector_type(2))) unsigned int u32x2;
typedef __attribute__((ext_vector_type(4))) unsigned int u32x4;

__device__ inline short f2bf(float f) {
    unsigned u = __float_as_uint(f);
    u += 0x7FFFu + ((u >> 16) & 1u);   // round-to-nearest-even
    return (short)(u >> 16);
}

// packed f32->bf16 (RNE), lo <- s0, hi <- s1
__device__ inline unsigned cvtpk(float lo, float hi) {
    unsigned r;
    asm volatile("v_cvt_pk_bf16_f32 %0, %1, %2" : "=v"(r) : "v"(lo), "v"(hi));
    return r;
}

__device__ inline f32x4 MFMA(short8 a, short8 b, f32x4 c) {
    return __builtin_amdgcn_mfma_f32_16x16x32_bf16(a, b, c, 0, 0, 0);
}

__device__ inline short8 load_w8s(const float* p, float s) {
    float4 a = *reinterpret_cast<const float4*>(p);
    float4 b = *reinterpret_cast<const float4*>(p + 4);
    short8 r;
    r[0] = f2bf(a.x * s); r[1] = f2bf(a.y * s); r[2] = f2bf(a.z * s); r[3] = f2bf(a.w * s);
    r[4] = f2bf(b.x * s); r[5] = f2bf(b.y * s); r[6] = f2bf(b.z * s); r[7] = f2bf(b.w * s);
    return r;
}
__device__ inline short8 load_w5s(const float* p, float s) {
    short8 r = (short8)0;
    r[0] = f2bf(p[0] * s); r[1] = f2bf(p[1] * s); r[2] = f2bf(p[2] * s);
    r[3] = f2bf(p[3] * s); r[4] = f2bf(p[4] * s);
    return r;
}

// 1024 threads = 16 waves, 256 blocks = 1 block/CU = 4 waves/SIMD.
// Same body as R5/R6 (occupancy 46% verified). Register control is now
// ATTRIBUTE-ONLY: __launch_bounds__ is REMOVED because it emits its own
// amdgpu-waves-per-eu (from arg2), which clobbered the explicit
// amdgpu_waves_per_eu(4,4) in R6 (VGPR stayed 64, 597 MB spill).
// amdgpu_flat_work_group_size(1024,1024) replaces launch_bounds' sizing
// role; amdgpu_waves_per_eu(4,4) pins the allocator to the 4-waves/EU
// budget (512/4 = 128 VGPR) and forbids squeezing toward 8 waves/EU.
// Per-wave live state ~118 regs: 15 short8 weights (60) + ah (16) +
// gate accumulators (16) + hreg (4) + x5 (5) + packing/addressing.
// Biases and head weights live in LDS to stay under 128.
// Wave w owns batch half a = w>>3, gate-cols 16*(w&7)..+16 of r/z/n:
// 15 MFMA + 4 elems/lane + 4 KB LDS read per wave per step; 4-way wave
// interleave per SIMD hides the serial read->MFMA->trans chain.
// Elementwise: combined denominator (validated R4): 3 exp2 + 2 rcp/elem.
__global__
__attribute__((amdgpu_flat_work_group_size(1024, 1024)))
__attribute__((amdgpu_waves_per_eu(4, 4)))
void gru_tracemodel_kernel(const float* __restrict__ obs, const float* __restrict__ target,
                           const float* __restrict__ eWih, const float* __restrict__ eWhh,
                           const float* __restrict__ ebih, const float* __restrict__ ebhh,
                           const float* __restrict__ cWih, const float* __restrict__ cWhh,
                           const float* __restrict__ cbih, const float* __restrict__ cbhh,
                           const float* __restrict__ headW, const float* __restrict__ headb,
                           float* __restrict__ out)
{
    __shared__ __attribute__((aligned(16))) short Abuf[2][BT][LDSTR];
    __shared__ __attribute__((aligned(16))) short Hw[DIN][LDSTR];     // head W, bf16
    __shared__ __attribute__((aligned(16))) float BiasLds[16][4][4][4]; // [wave][g][q][r]
    __shared__ float HbLds[8];

    const int tid   = threadIdx.x;
    const int wave  = tid >> 6;    // 0..15
    const int lane  = tid & 63;
    const int q     = lane >> 4;   // k-group of A/B frags; row-group of C/D
    const int c     = lane & 15;   // non-K index of A/B frags; col of C/D
    const int b0    = blockIdx.x * BT;
    const int a     = wave >> 3;   // batch half-tile (0 or 1)
    const int w8    = wave & 7;    // gate-col slice
    const int wbase = w8 * 16;

    // h0 = 0
    for (int i = tid; i < 2 * BT * LDSTR; i += NTHR) ((short*)Abuf)[i] = 0;

    // ---- weight fragments (A-operand: lane holds W'[n = wbase+c][k]) ----
    // kt 0..3: Whh K-tiles; kt 4: zero-padded Wih x-tile (only q==0 nonzero)
    short8 Wr[5], Wz[5], Wn[5];

    auto load_phase = [&](const float* Wih, const float* Whh,
                          const float* bih, const float* bhh) {
        const int nr = 0 * HD + wbase + c;
        const int nz = 1 * HD + wbase + c;
        const int nn = 2 * HD + wbase + c;
        #pragma unroll
        for (int kt = 0; kt < 4; ++kt) {
            Wr[kt] = load_w8s(Whh + nr * HD + kt * 32 + q * 8, LOG2E);
            Wz[kt] = load_w8s(Whh + nz * HD + kt * 32 + q * 8, LOG2E);
            Wn[kt] = load_w8s(Whh + nn * HD + kt * 32 + q * 8, 2.f * LOG2E);
        }
        Wr[4] = (q == 0) ? load_w5s(Wih + nr * DIN, LOG2E) : (short8)0;
        Wz[4] = (q == 0) ? load_w5s(Wih + nz * DIN, LOG2E) : (short8)0;
        Wn[4] = (q == 0) ? load_w5s(Wih + nn * DIN, 2.f * LOG2E) : (short8)0;
        // biases -> this wave's LDS slot (f32, exact); lane c==0 of each q
        if (c == 0) {
            const int n0 = wbase + q * 4;
            f32x4 v0, v1, v2, v3;
            #pragma unroll
            for (int r = 0; r < 4; ++r) {
                v0[r] = (bih[0 * HD + n0 + r] + bhh[0 * HD + n0 + r]) * LOG2E;
                v1[r] = (bih[1 * HD + n0 + r] + bhh[1 * HD + n0 + r]) * LOG2E;
                v2[r] = bih[2 * HD + n0 + r] * (2.f * LOG2E);
                v3[r] = bhh[2 * HD + n0 + r] * (2.f * LOG2E);
            }
            *reinterpret_cast<f32x4*>(&BiasLds[wave][0][q][0]) = v0;
            *reinterpret_cast<f32x4*>(&BiasLds[wave][1][q][0]) = v1;
            *reinterpret_cast<f32x4*>(&BiasLds[wave][2][q][0]) = v2;
            *reinterpret_cast<f32x4*>(&BiasLds[wave][3][q][0]) = v3;
        }
    };
    load_phase(eWih, eWhh, ebih, ebhh);

    // head weights -> LDS once (wave 0); covered by first loop barrier
    if (wave == 0 && c < DIN) {
        #pragma unroll
        for (int kt = 0; kt < 4; ++kt) {
            short8 w = load_w8s(headW + c * HD + kt * 32 + q * 8, 1.f);
            *reinterpret_cast<short8*>(&Hw[c][kt * 32 + q * 8]) = w;
        }
    }
    if (tid < 8) HbLds[tid] = (tid < DIN) ? headb[tid] : 0.f;

    // fp32 carried h: hreg[r] = h[batch a*16+c][dim wbase+q*4+r]
    float hreg[4] = {0.f, 0.f, 0.f, 0.f};

    const float* obsr = obs    + (size_t)(b0 + a * 16 + c) * (T_OBS * DIN);
    const float* tgtr = target + (size_t)(b0 + a * 16 + c) * (T_FUT * DIN);
    float x5[5] = {0, 0, 0, 0, 0};
    if (q == 0) {
        #pragma unroll
        for (int j = 0; j < DIN; ++j) x5[j] = obsr[j];   // x_0
    }

    for (int t = 0; t <= T_ALL; ++t) {
        __syncthreads();
        const int p = t & 1;

        // h fragments (B-operand): lane holds h[batch a*16+c][k=kt*32+q*8..]
        short8 ah[4];
        const short* ap = &Abuf[p][a * 16 + c][0];
        #pragma unroll
        for (int kt = 0; kt < 4; ++kt)
            ah[kt] = *reinterpret_cast<const short8*>(ap + kt * 32 + q * 8);

        // fused head on previous step's h; firing wave rotates over the 8
        // gate-col slices; both batch halves fire (one wave each)
        if (t >= T_OBS + 1 && w8 == ((t - T_OBS - 1) & 7)) {
            const int s = t - (T_OBS + 1);
            const short* hwp = &Hw[(c < DIN) ? c : 0][0];
            f32x4 acc = {0.f, 0.f, 0.f, 0.f};
            #pragma unroll
            for (int kt = 0; kt < 4; ++kt) {
                short8 wh = *reinterpret_cast<const short8*>(hwp + kt * 32 + q * 8);
                acc = MFMA(wh, ah[kt], acc);
            }
            const int d0 = q * 4;
            if (d0 < DIN) {
                float* op = out + ((size_t)(b0 + a * 16 + c) * T_FUT + s) * DIN + d0;
                op[0] = acc[0] + HbLds[d0];
                if (q == 0) {
                    op[1] = acc[1] + HbLds[1];
                    op[2] = acc[2] + HbLds[2];
                    op[3] = acc[3] + HbLds[3];
                }
            }
        }
        if (t == T_ALL) break;

        if (t == T_OBS) load_phase(cWih, cWhh, cbih, cbhh);  // switch to cell

        // x fragment (5th K-tile, B-operand): q==0 lanes hold x[batch][0..4]
        short8 ax;
        {
            unsigned u0 = 0, u1 = 0, u2 = 0;
            if (q == 0) {
                u0 = cvtpk(x5[0], x5[1]);
                u1 = cvtpk(x5[2], x5[3]);
                u2 = cvtpk(x5[4], 0.f);
            }
            u32x4 va = {u0, u1, u2, 0u};
            ax = __builtin_bit_cast(short8, va);
            const int tn = t + 1;   // prefetch next step's x
            if (q == 0 && tn < T_ALL) {
                const float* px = (tn < T_OBS)  ? (obsr + tn * DIN)
                                : (tn == T_OBS) ? (obsr + (T_OBS - 1) * DIN)
                                                : (tgtr + (tn - T_OBS - 1) * DIN);
                #pragma unroll
                for (int j = 0; j < DIN; ++j) x5[j] = px[j];
            }
        }

        // bias C-init: per-wave LDS broadcast reads (same addr across c-lanes)
        const f32x4 bR  = *reinterpret_cast<const f32x4*>(&BiasLds[wave][0][q][0]);
        const f32x4 bZ  = *reinterpret_cast<const f32x4*>(&BiasLds[wave][1][q][0]);
        const f32x4 bNi = *reinterpret_cast<const f32x4*>(&BiasLds[wave][2][q][0]);
        const f32x4 bNh = *reinterpret_cast<const f32x4*>(&BiasLds[wave][3][q][0]);

        // gate MFMAs (A = weights, B = h): 15/wave/step
        f32x4 aR  = MFMA(Wr[0], ah[0], bR);
        f32x4 aZ  = MFMA(Wz[0], ah[0], bZ);
        f32x4 aNh = MFMA(Wn[0], ah[0], bNh);
        #pragma unroll
        for (int kt = 1; kt < 4; ++kt) {
            aR  = MFMA(Wr[kt], ah[kt], aR);
            aZ  = MFMA(Wz[kt], ah[kt], aZ);
            aNh = MFMA(Wn[kt], ah[kt], aNh);
        }
        aR  = MFMA(Wr[4], ax, aR);
        aZ  = MFMA(Wz[4], ax, aZ);
        f32x4 aNi = MFMA(Wn[4], ax, bNi);

        // elementwise: accumulators pre-scaled by log2e (2log2e for n).
        // rv = 1/(1+exp2(-aR)); y = aNi + rv*aNh; ey = exp2(y); ez = exp2(-aZ)
        // h' = (h*(1+ey) + ez*(ey-1)) / ((1+ez)*(1+ey))   [validated R4]
        float hn[4];
        #pragma unroll
        for (int r = 0; r < 4; ++r) {
            float er  = __builtin_amdgcn_exp2f(-aR[r]);
            float rv  = __builtin_amdgcn_rcpf(1.f + er);
            float yv  = fmaf(rv, aNh[r], aNi[r]);
            float ey  = __builtin_amdgcn_exp2f(yv);
            float ez  = __builtin_amdgcn_exp2f(-aZ[r]);
            float d2  = 1.f + ey;
            float d1  = 1.f + ez;
            float em1 = ey - 1.f;
            float num = fmaf(ez, em1, hreg[r] * d2);
            float h_  = num * __builtin_amdgcn_rcpf(d1 * d2);
            hreg[r] = h_;
            hn[r] = h_;
        }
        // writeback: 4 consecutive h-dims of one row -> one b64 store
        u32x2 wv = { cvtpk(hn[0], hn[1]), cvtpk(hn[2], hn[3]) };
        *reinterpret_cast<u32x2*>(&Abuf[1 - p][a * 16 + c][wbase + q * 4]) = wv;
    }
}

extern "C" void kernel_launch(void* const* d_in, const int* in_sizes, int n_in,
                              void* d_out, int out_size, void* d_ws, size_t ws_size,
                              hipStream_t stream)
{
    (void)in_sizes; (void)n_in; (void)d_ws; (void)ws_size; (void)out_size;
    gru_tracemodel_kernel<<<dim3(B_TOT / BT), dim3(NTHR), 0, stream>>>(
        (const float*)d_in[0],  (const float*)d_in[1],
        (const float*)d_in[2],  (const float*)d_in[3],
        (const float*)d_in[4],  (const float*)d_in[5],
        (const float*)d_in[6],  (const float*)d_in[7],
        (const float*)d_in[8],  (const float*)d_in[9],
        (const float*)d_in[10], (const float*)d_in[11],
        (float*)d_out);
}

// Round 9
// 336.393 us; speedup vs baseline: 2.5660x; 2.5031x over previous
//
#include <hip/hip_runtime.h>

#define B_TOT 8192
#define T_OBS 128
#define T_FUT 64
#define T_ALL 192
#define DIN 5
#define HD 128
#define BT 32          // batch rows per block (two 16-row tiles)
#define LDSTR 136      // LDS row stride in shorts (272 B, 16B-aligned rows)

#define LOG2E 1.44269504088896340736f

typedef __attribute__((ext_vector_type(8))) short short8;
typedef __attribute__((ext_vector_type(4))) float f32x4;
typedef __attribute__((ext_vector_type(2))) unsigned int u32x2;
typedef __attribute__((ext_vector_type(4))) unsigned int u32x4;

__device__ inline short f2bf(float f) {
    unsigned u = __float_as_uint(f);
    u += 0x7FFFu + ((u >> 16) & 1u);   // round-to-nearest-even
    return (short)(u >> 16);
}

// packed f32->bf16 (RNE), lo <- s0, hi <- s1
__device__ inline unsigned cvtpk(float lo, float hi) {
    unsigned r;
    asm volatile("v_cvt_pk_bf16_f32 %0, %1, %2" : "=v"(r) : "v"(lo), "v"(hi));
    return r;
}

__device__ inline f32x4 MFMA(short8 a, short8 b, f32x4 c) {
    return __builtin_amdgcn_mfma_f32_16x16x32_bf16(a, b, c, 0, 0, 0);
}

__device__ inline short8 load_w8s(const float* p, float s) {
    float4 a = *reinterpret_cast<const float4*>(p);
    float4 b = *reinterpret_cast<const float4*>(p + 4);
    short8 r;
    r[0] = f2bf(a.x * s); r[1] = f2bf(a.y * s); r[2] = f2bf(a.z * s); r[3] = f2bf(a.w * s);
    r[4] = f2bf(b.x * s); r[5] = f2bf(b.y * s); r[6] = f2bf(b.z * s); r[7] = f2bf(b.w * s);
    return r;
}
__device__ inline short8 load_w5s(const float* p, float s) {
    short8 r = (short8)0;
    r[0] = f2bf(p[0] * s); r[1] = f2bf(p[1] * s); r[2] = f2bf(p[2] * s);
    r[3] = f2bf(p[3] * s); r[4] = f2bf(p[4] * s);
    return r;
}

// 512 threads = 8 waves, 256 blocks = 1 block/CU (R3 anchor structure,
// 300 us verified, VGPR=112 no-spill). Wave w owns gate-cols [16w,16w+16)
// of each of r/z/n (15 short8 weight frags = 60 VGPR); block owns 32
// batch rows as two 16-row B-tiles. Swapped MFMA (A=weights, B=h^T):
// lane's C/D holds 4 consecutive gate-dims of one batch row -> writeback
// is 2 cvt_pk + 1 b64 store.
//
// TOOLCHAIN NOTE (R1/R4/R5/R6/R7 evidence): any config requesting >8
// waves/CU (1024-thr blocks, or (512,4)) gets a 64-VGPR cap regardless of
// launch_bounds / amdgpu_waves_per_eu / flat_work_group_size, and the
// 60-reg weight set spills ~600 MB of scratch. Do not revisit. 512 thr +
// launch_bounds(512,1) is the proven register-safe point.
//
// R8 deltas vs R3: (a) combined-denominator elementwise, 3 exp2 + 2 rcp
// per element (was 3+3; validated absmax-identical in R4-R7);
// (b) x-pack cvtpk unconditional (q>=1 lanes produce garbage that
// multiplies the zeroed weight K-rows -> exact 0 contribution).
__global__ __launch_bounds__(512, 1)
void gru_tracemodel_kernel(const float* __restrict__ obs, const float* __restrict__ target,
                           const float* __restrict__ eWih, const float* __restrict__ eWhh,
                           const float* __restrict__ ebih, const float* __restrict__ ebhh,
                           const float* __restrict__ cWih, const float* __restrict__ cWhh,
                           const float* __restrict__ cbih, const float* __restrict__ cbhh,
                           const float* __restrict__ headW, const float* __restrict__ headb,
                           float* __restrict__ out)
{
    __shared__ __attribute__((aligned(16))) short Abuf[2][BT][LDSTR];

    const int tid   = threadIdx.x;
    const int wave  = tid >> 6;    // 0..7
    const int lane  = tid & 63;
    const int q     = lane >> 4;   // k-group of A/B frags; row-group of C/D
    const int c     = lane & 15;   // non-K index of A/B frags; col of C/D
    const int b0    = blockIdx.x * BT;
    const int wbase = wave * 16;   // this wave's gate-column slice

    // h0 = 0
    for (int i = tid; i < 2 * BT * LDSTR; i += 512) ((short*)Abuf)[i] = 0;

    // ---- weight fragments (A-operand: lane holds W'[n = wbase+c][k]) ----
    // kt 0..3: Whh K-tiles; kt 4: zero-padded Wih x-tile (only q==0 nonzero)
    short8 Wr[5], Wz[5], Wn[5];
    f32x4  br4, bz4, bnh4, bni4;   // per-reg biases: n = wbase + q*4 + r

    auto load_phase = [&](const float* Wih, const float* Whh,
                          const float* bih, const float* bhh) {
        const int nr = 0 * HD + wbase + c;
        const int nz = 1 * HD + wbase + c;
        const int nn = 2 * HD + wbase + c;
        #pragma unroll
        for (int kt = 0; kt < 4; ++kt) {
            Wr[kt] = load_w8s(Whh + nr * HD + kt * 32 + q * 8, LOG2E);
            Wz[kt] = load_w8s(Whh + nz * HD + kt * 32 + q * 8, LOG2E);
            Wn[kt] = load_w8s(Whh + nn * HD + kt * 32 + q * 8, 2.f * LOG2E);
        }
        Wr[4] = (q == 0) ? load_w5s(Wih + nr * DIN, LOG2E) : (short8)0;
        Wz[4] = (q == 0) ? load_w5s(Wih + nz * DIN, LOG2E) : (short8)0;
        Wn[4] = (q == 0) ? load_w5s(Wih + nn * DIN, 2.f * LOG2E) : (short8)0;
        const int n0 = wbase + q * 4;
        #pragma unroll
        for (int r = 0; r < 4; ++r) {
            br4[r]  = (bih[0 * HD + n0 + r] + bhh[0 * HD + n0 + r]) * LOG2E;
            bz4[r]  = (bih[1 * HD + n0 + r] + bhh[1 * HD + n0 + r]) * LOG2E;
            bni4[r] = bih[2 * HD + n0 + r] * (2.f * LOG2E);
            bnh4[r] = bhh[2 * HD + n0 + r] * (2.f * LOG2E);
        }
    };
    load_phase(eWih, eWhh, ebih, ebhh);

    // head fragments (all waves hold them; firing wave rotates per step).
    // A-operand: lane c holds headW[d = c][k] (unscaled), d < 5.
    short8 Whd[4];
    f32x4  hb4;
    #pragma unroll
    for (int kt = 0; kt < 4; ++kt)
        Whd[kt] = (c < DIN) ? load_w8s(headW + c * HD + kt * 32 + q * 8, 1.f) : (short8)0;
    #pragma unroll
    for (int r = 0; r < 4; ++r)
        hb4[r] = (q * 4 + r < DIN) ? headb[q * 4 + r] : 0.f;

    // fp32 carried h: hreg[a][r] = h[batch a*16+c][gate-dim wbase+q*4+r]
    float hreg[2][4] = {{0.f,0.f,0.f,0.f},{0.f,0.f,0.f,0.f}};

    const float* obsr[2] = { obs + (size_t)(b0 + c) * (T_OBS * DIN),
                             obs + (size_t)(b0 + 16 + c) * (T_OBS * DIN) };
    const float* tgtr[2] = { target + (size_t)(b0 + c) * (T_FUT * DIN),
                             target + (size_t)(b0 + 16 + c) * (T_FUT * DIN) };
    float x5[2][5] = {{0,0,0,0,0},{0,0,0,0,0}};
    if (q == 0) {
        #pragma unroll
        for (int a = 0; a < 2; ++a)
            #pragma unroll
            for (int j = 0; j < DIN; ++j) x5[a][j] = obsr[a][j];   // x_0
    }

    for (int t = 0; t <= T_ALL; ++t) {
        __syncthreads();
        const int p = t & 1;

        // h fragments (B-operand): lane holds h[batch a*16+c][k=kt*32+q*8..]
        short8 ah[2][4];
        #pragma unroll
        for (int a = 0; a < 2; ++a) {
            const short* ap = &Abuf[p][a * 16 + c][0];
            #pragma unroll
            for (int kt = 0; kt < 4; ++kt)
                ah[a][kt] = *reinterpret_cast<const short8*>(ap + kt * 32 + q * 8);
        }

        // fused head on previous step's h; firing wave rotates to balance skew
        if (t >= T_OBS + 1 && wave == ((t - T_OBS - 1) & 7)) {
            const int s = t - (T_OBS + 1);
            const int d0 = q * 4;
            #pragma unroll
            for (int a = 0; a < 2; ++a) {
                f32x4 acc = hb4;
                #pragma unroll
                for (int kt = 0; kt < 4; ++kt)
                    acc = MFMA(Whd[kt], ah[a][kt], acc);
                // D[d = q*4+r][batch = a*16+c]
                if (d0 < DIN) {
                    float* op = out + ((size_t)(b0 + a * 16 + c) * T_FUT + s) * DIN + d0;
                    op[0] = acc[0];
                    if (q == 0) { op[1] = acc[1]; op[2] = acc[2]; op[3] = acc[3]; }
                }
            }
        }
        if (t == T_ALL) break;

        if (t == T_OBS) load_phase(cWih, cWhh, cbih, cbhh);  // switch to cell

        // x fragment (5th K-tile, B-operand). cvtpk runs unmasked: q>=1
        // lanes carry garbage that multiplies zeroed weight K-rows -> 0.
        short8 ax[2];
        {
            u32x4 va = { cvtpk(x5[0][0], x5[0][1]),
                         cvtpk(x5[0][2], x5[0][3]),
                         cvtpk(x5[0][4], 0.f), 0u };
            u32x4 vb = { cvtpk(x5[1][0], x5[1][1]),
                         cvtpk(x5[1][2], x5[1][3]),
                         cvtpk(x5[1][4], 0.f), 0u };
            ax[0] = __builtin_bit_cast(short8, va);
            ax[1] = __builtin_bit_cast(short8, vb);
            const int tn = t + 1;   // prefetch next step's x (masked loads)
            if (q == 0 && tn < T_ALL) {
                #pragma unroll
                for (int a = 0; a < 2; ++a) {
                    const float* px = (tn < T_OBS)  ? (obsr[a] + tn * DIN)
                                    : (tn == T_OBS) ? (obsr[a] + (T_OBS - 1) * DIN)
                                                    : (tgtr[a] + (tn - T_OBS - 1) * DIN);
                    #pragma unroll
                    for (int j = 0; j < DIN; ++j) x5[a][j] = px[j];
                }
            }
        }

        // gate MFMAs (A = weights, B = h): 30/wave/step
        #pragma unroll
        for (int a = 0; a < 2; ++a) {
            f32x4 aR  = MFMA(Wr[0], ah[a][0], br4);
            f32x4 aZ  = MFMA(Wz[0], ah[a][0], bz4);
            f32x4 aNh = MFMA(Wn[0], ah[a][0], bnh4);
            #pragma unroll
            for (int kt = 1; kt < 4; ++kt) {
                aR  = MFMA(Wr[kt], ah[a][kt], aR);
                aZ  = MFMA(Wz[kt], ah[a][kt], aZ);
                aNh = MFMA(Wn[kt], ah[a][kt], aNh);
            }
            aR  = MFMA(Wr[4], ax[a], aR);
            aZ  = MFMA(Wz[4], ax[a], aZ);
            f32x4 aNi = MFMA(Wn[4], ax[a], bni4);

            // elementwise: accumulators pre-scaled by log2e (2log2e for n).
            // rv = 1/(1+exp2(-aR)); y = aNi + rv*aNh; ey = exp2(y);
            // ez = exp2(-aZ);  h' = (h*(1+ey) + ez*(ey-1)) / ((1+ez)*(1+ey))
            // 3 exp2 + 2 rcp per element (validated R4-R7, absmax 0.0039).
            float hn[4];
            #pragma unroll
            for (int r = 0; r < 4; ++r) {
                float er  = __builtin_amdgcn_exp2f(-aR[r]);
                float rv  = __builtin_amdgcn_rcpf(1.f + er);
                float yv  = fmaf(rv, aNh[r], aNi[r]);
                float ey  = __builtin_amdgcn_exp2f(yv);
                float ez  = __builtin_amdgcn_exp2f(-aZ[r]);
                float d2  = 1.f + ey;
                float d1  = 1.f + ez;
                float em1 = ey - 1.f;
                float num = fmaf(ez, em1, hreg[a][r] * d2);
                float h_  = num * __builtin_amdgcn_rcpf(d1 * d2);
                hreg[a][r] = h_;
                hn[r] = h_;
            }
            // writeback: 4 consecutive gate-dims of one row -> one b64 store
            u32x2 wv = { cvtpk(hn[0], hn[1]), cvtpk(hn[2], hn[3]) };
            *reinterpret_cast<u32x2*>(&Abuf[1 - p][a * 16 + c][wbase + q * 4]) = wv;
        }
    }
}

extern "C" void kernel_launch(void* const* d_in, const int* in_sizes, int n_in,
                              void* d_out, int out_size, void* d_ws, size_t ws_size,
                              hipStream_t stream)
{
    (void)in_sizes; (void)n_in; (void)d_ws; (void)ws_size; (void)out_size;
    gru_tracemodel_kernel<<<dim3(B_TOT / BT), dim3(512), 0, stream>>>(
        (const float*)d_in[0],  (const float*)d_in[1],
        (const float*)d_in[2],  (const float*)d_in[3],
        (const float*)d_in[4],  (const float*)d_in[5],
        (const float*)d_in[6],  (const float*)d_in[7],
        (const float*)d_in[8],  (const float*)d_in[9],
        (const float*)d_in[10], (const float*)d_in[11],
        (float*)d_out);
}